// Round 4
// baseline (587.439 us; speedup 1.0000x reference)
//
#include <hip/hip_runtime.h>
#include <math.h>

#define NB 4
#define TT 2048
#define EE 768
#define HH 12
#define DD 64
#define NH (NB*HH)                          // 48
#define PLANE_S ((size_t)NH * TT * DD)      // 6291456 ushorts per bf16 plane
#define WMAT (EE*EE)                        // 589824
#define XSZ ((size_t)NB * TT * EE)          // 6291456
#define QSCALE 0.18033688011112042f         // 0.125 * log2(e): base-2 softmax

typedef __attribute__((ext_vector_type(8))) short s8b;   // 8 bf16 (4 VGPR)
typedef __attribute__((ext_vector_type(4))) float f4;    // MFMA C/D

// fp32 -> bf16 RNE and hi/lo split: x ~= hi + lo, err ~ 2^-18 |x|
__device__ inline unsigned short bfh(float x) {
    unsigned u = __float_as_uint(x);
    return (unsigned short)((u + 0x7fffu + ((u >> 16) & 1u)) >> 16);
}
__device__ inline float bff(unsigned short s) { return __uint_as_float(((unsigned)s) << 16); }
__device__ inline void split1(float x, unsigned short& h, unsigned short& l) {
    h = bfh(x); l = bfh(x - bff(h));
}
__device__ inline float fexp2(float x) {
#if __has_builtin(__builtin_amdgcn_exp2f)
    return __builtin_amdgcn_exp2f(x);
#else
    return __expf(x * 0.6931471805599453f);
#endif
}

// ---------------------------------------------------------------------------
// Kernel 0a: pre-split x to bf16 hi/lo planes (kills the 12x redundant
// in-loop split in qkv). Kernel 0b: same for weights.
// ---------------------------------------------------------------------------
__global__ __launch_bounds__(256) void prep_x(
    const float* __restrict__ x, unsigned short* __restrict__ xh,
    unsigned short* __restrict__ xl)
{
    const int base = blockIdx.x * 1024 + threadIdx.x * 4;
    float4 v = *(const float4*)&x[base];
    unsigned short h0,l0,h1,l1,h2,l2,h3,l3;
    split1(v.x,h0,l0); split1(v.y,h1,l1); split1(v.z,h2,l2); split1(v.w,h3,l3);
    *(short4*)&xh[base] = make_short4((short)h0,(short)h1,(short)h2,(short)h3);
    *(short4*)&xl[base] = make_short4((short)l0,(short)l1,(short)l2,(short)l3);
}

__global__ __launch_bounds__(256) void prep_w(
    const float* __restrict__ Wq, const float* __restrict__ Wk,
    const float* __restrict__ Wv, unsigned short* __restrict__ wh,
    unsigned short* __restrict__ wl)
{
    const int mat = blockIdx.y;
    const float* __restrict__ W = (mat == 0) ? Wq : (mat == 1) ? Wk : Wv;
    const int base = blockIdx.x * 1024 + threadIdx.x * 4;
    float4 v = *(const float4*)&W[base];
    unsigned short h0,l0,h1,l1,h2,l2,h3,l3;
    split1(v.x,h0,l0); split1(v.y,h1,l1); split1(v.z,h2,l2); split1(v.w,h3,l3);
    size_t o = (size_t)mat * WMAT + base;
    *(short4*)&wh[o] = make_short4((short)h0,(short)h1,(short)h2,(short)h3);
    *(short4*)&wl[o] = make_short4((short)l0,(short)l1,(short)l2,(short)l3);
}

// ---------------------------------------------------------------------------
// Kernel 1: fused QKV projection (bf16x3 MFMA), pure-copy staging from
// pre-split planes, register-prefetched. Writes Qh/Ql (pre-scaled), Kh/Kl
// as [nh][t][d]; Vth/Vtl TRANSPOSED [nh][d][t'] with t' permuted within
// each 64-key group by s(u)=(u&15)*4+(u>>4) — matches attn's P storage
// order (shared k-permutation, numerically exact).
// ---------------------------------------------------------------------------
__global__ __launch_bounds__(256, 3) void qkv_mfma(
    const unsigned short* __restrict__ xh,
    const unsigned short* __restrict__ xl,
    const unsigned short* __restrict__ whp,
    const unsigned short* __restrict__ wlp,
    unsigned short* __restrict__ ws)
{
    const int mt  = blockIdx.x;     // 0..63
    const int h   = blockIdx.y;     // 0..11
    const int tid = threadIdx.x;
    const int w    = tid >> 6;
    const int ln   = tid & 63;
    const int quad = ln >> 4;
    const int lcol = ln & 15;

    union Smem {
        struct { unsigned short Ah[128][40], Al[128][40],
                                Bh[3][64][40], Bl[3][64][40]; } s;   // 51200 B
        struct { unsigned short Vh[64][136], Vl[64][136]; } t;        // 34816 B
    };
    __shared__ __align__(16) union Smem u;

    f4 acc[3][2][4];
    #pragma unroll
    for (int s = 0; s < 3; ++s)
        #pragma unroll
        for (int rt = 0; rt < 2; ++rt)
            #pragma unroll
            for (int ct = 0; ct < 4; ++ct)
                acc[s][rt][ct] = f4{0.f, 0.f, 0.f, 0.f};

    const int m0 = mt * 128;

    // Per-thread staging coords
    const int ar0 = tid >> 2,  ag0 = tid & 3;          // A: +0 / +64 rows
    const int br  = tid >> 2,  bg  = tid & 3;          // B: per-mat

    for (int kt = 0; kt < EE; kt += 32) {
        // Prefetch to regs BEFORE barrier (hide L2 latency under prev MFMA)
        uint4 pAh[2], pAl[2], pBh[3], pBl[3];
        #pragma unroll
        for (int r = 0; r < 2; ++r) {
            size_t go = (size_t)(m0 + ar0 + r * 64) * EE + kt + ag0 * 8;
            pAh[r] = *(const uint4*)&xh[go];
            pAl[r] = *(const uint4*)&xl[go];
        }
        #pragma unroll
        for (int r = 0; r < 3; ++r) {
            size_t go = (size_t)r * WMAT + (size_t)(h * 64 + br) * EE + kt + bg * 8;
            pBh[r] = *(const uint4*)&whp[go];
            pBl[r] = *(const uint4*)&wlp[go];
        }
        __syncthreads();
        #pragma unroll
        for (int r = 0; r < 2; ++r) {
            *(uint4*)&u.s.Ah[ar0 + r * 64][ag0 * 8] = pAh[r];
            *(uint4*)&u.s.Al[ar0 + r * 64][ag0 * 8] = pAl[r];
        }
        #pragma unroll
        for (int r = 0; r < 3; ++r) {
            *(uint4*)&u.s.Bh[r][br][bg * 8] = pBh[r];
            *(uint4*)&u.s.Bl[r][br][bg * 8] = pBl[r];
        }
        __syncthreads();

        s8b ah[2], al[2];
        #pragma unroll
        for (int rt = 0; rt < 2; ++rt) {
            ah[rt] = *(const s8b*)&u.s.Ah[w * 32 + rt * 16 + lcol][quad * 8];
            al[rt] = *(const s8b*)&u.s.Al[w * 32 + rt * 16 + lcol][quad * 8];
        }
        #pragma unroll
        for (int s = 0; s < 3; ++s)
            #pragma unroll
            for (int ct = 0; ct < 4; ++ct) {
                s8b bh = *(const s8b*)&u.s.Bh[s][ct * 16 + lcol][quad * 8];
                s8b bl = *(const s8b*)&u.s.Bl[s][ct * 16 + lcol][quad * 8];
                #pragma unroll
                for (int rt = 0; rt < 2; ++rt) {
                    acc[s][rt][ct] = __builtin_amdgcn_mfma_f32_16x16x32_bf16(ah[rt], bh, acc[s][rt][ct], 0, 0, 0);
                    acc[s][rt][ct] = __builtin_amdgcn_mfma_f32_16x16x32_bf16(ah[rt], bl, acc[s][rt][ct], 0, 0, 0);
                    acc[s][rt][ct] = __builtin_amdgcn_mfma_f32_16x16x32_bf16(al[rt], bh, acc[s][rt][ct], 0, 0, 0);
                }
            }
    }

    unsigned short* qhp = ws;
    unsigned short* qlp = ws + PLANE_S;
    unsigned short* khp = ws + 2 * PLANE_S;
    unsigned short* klp = ws + 3 * PLANE_S;
    unsigned short* vthp = ws + 4 * PLANE_S;
    unsigned short* vtlp = ws + 5 * PLANE_S;

    const int n = m0 >> 11;
    const int tb = m0 & 2047;
    const int nh = n * HH + h;

    // Q (scaled) and K: direct hi/lo stores, [nh][t][d]
    #pragma unroll
    for (int rt = 0; rt < 2; ++rt)
        #pragma unroll
        for (int reg = 0; reg < 4; ++reg) {
            int t = tb + w * 32 + rt * 16 + quad * 4 + reg;
            size_t ro = ((size_t)nh * TT + t) * DD;
            #pragma unroll
            for (int ct = 0; ct < 4; ++ct) {
                unsigned short hi, lo;
                split1(acc[0][rt][ct][reg] * QSCALE, hi, lo);
                qhp[ro + ct * 16 + lcol] = hi;
                qlp[ro + ct * 16 + lcol] = lo;
                split1(acc[1][rt][ct][reg], hi, lo);
                khp[ro + ct * 16 + lcol] = hi;
                klp[ro + ct * 16 + lcol] = lo;
            }
        }

    // V: transpose+permute through LDS -> [nh][d][t']
    // local row u = (w&1)*32 + rt*16 + quad*4 + reg in its 64-group (grp=w>>1)
    // permuted slot s(u) = (u&15)*4 + (u>>4) = (quad*4+reg)*4 + (w&1)*2 + rt
    __syncthreads();
    #pragma unroll
    for (int rt = 0; rt < 2; ++rt)
        #pragma unroll
        for (int reg = 0; reg < 4; ++reg) {
            int slot = (w >> 1) * 64 + (quad * 4 + reg) * 4 + (w & 1) * 2 + rt;
            #pragma unroll
            for (int ct = 0; ct < 4; ++ct) {
                unsigned short hi, lo;
                split1(acc[2][rt][ct][reg], hi, lo);
                u.t.Vh[ct * 16 + lcol][slot] = hi;
                u.t.Vl[ct * 16 + lcol][slot] = lo;
            }
        }
    __syncthreads();
    #pragma unroll
    for (int r = 0; r < 8; ++r) {
        int idx = tid + r * 256;             // 2048 granules: [pl][d][gg]
        int pl = idx >> 10, rem = idx & 1023;
        int d = rem >> 4, gg = rem & 15;
        uint4 v = (pl == 0) ? *(const uint4*)&u.t.Vh[d][gg * 8]
                            : *(const uint4*)&u.t.Vl[d][gg * 8];
        unsigned short* dst = (pl == 0) ? vthp : vtlp;
        *(uint4*)&dst[(size_t)nh * (DD * TT) + (size_t)d * TT + tb + gg * 8] = v;
    }
}

// ---------------------------------------------------------------------------
// Kernel 2: MFMA flash attention, fixed-max base-2 softmax, k-permuted P.
// Block = 256 thr (4 waves), Bq=128, Bk=64. P stored via b64 short4 into
// the permuted slot order matching Vt's t' axis (exact reordering).
// LDS = 36.9 KB; 3 blocks/CU = 768 = grid (zero tail).
// ---------------------------------------------------------------------------
__global__ __launch_bounds__(256, 3) void attn_mfma(
    const unsigned short* __restrict__ ws, float* __restrict__ out)
{
    const int bid = blockIdx.x;          // 0..767
    const int xcd = bid & 7;
    const int r0  = bid >> 3;
    const int qt  = r0 & 15;
    const int nh  = xcd * 6 + (r0 >> 4); // all 16 q-tiles of an nh on one XCD
    const int nn  = nh / HH, hh = nh % HH;

    const int tid = threadIdx.x;
    const int w    = tid >> 6;
    const int ln   = tid & 63;
    const int quad = ln >> 4;
    const int lcol = ln & 15;

    const unsigned short* qhp = ws                + (size_t)nh * (TT * DD);
    const unsigned short* qlp = ws +     PLANE_S  + (size_t)nh * (TT * DD);
    const unsigned short* khp = ws + 2 * PLANE_S  + (size_t)nh * (TT * DD);
    const unsigned short* klp = ws + 3 * PLANE_S  + (size_t)nh * (TT * DD);
    const unsigned short* vthp = ws + 4 * PLANE_S + (size_t)nh * (DD * TT);
    const unsigned short* vtlp = ws + 5 * PLANE_S + (size_t)nh * (DD * TT);

    __shared__ __align__(16) unsigned short Kh[64][72], Kl[64][72];
    __shared__ __align__(16) unsigned short Vth[64][72], Vtl[64][72];

    // Q fragments from pre-scaled hi/lo planes (b128 global loads, once)
    s8b qh[2][2], ql[2][2];
    #pragma unroll
    for (int rt = 0; rt < 2; ++rt)
        #pragma unroll
        for (int kk = 0; kk < 2; ++kk) {
            int qrow = qt * 128 + w * 32 + rt * 16 + lcol;
            size_t o = (size_t)qrow * DD + kk * 32 + quad * 8;
            qh[rt][kk] = *(const s8b*)&qhp[o];
            ql[rt][kk] = *(const s8b*)&qlp[o];
        }

    f4 acco[2][4];
    float lsum[2][4];
    #pragma unroll
    for (int rt = 0; rt < 2; ++rt)
        #pragma unroll
        for (int j = 0; j < 4; ++j) { acco[rt][j] = f4{0.f,0.f,0.f,0.f}; lsum[rt][j] = 0.f; }

    unsigned short (* __restrict__ Pb)[72] = (w < 2) ? Kh : Kl;
    const int pbase = (w & 1) * 32;

    const int sr = tid >> 3, sg = tid & 7;   // staging coords (512 granules/plane)

    for (int kt = 0; kt < TT / 64; ++kt) {
        // Prefetch K/V tile to regs before the barrier
        uint4 pK[2][2], pV[2][2];
        #pragma unroll
        for (int r = 0; r < 2; ++r) {
            int idx = tid + r * 256;
            pK[r][0] = *(const uint4*)&khp[(size_t)kt * 4096 + idx * 8];
            pK[r][1] = *(const uint4*)&klp[(size_t)kt * 4096 + idx * 8];
            size_t vo = (size_t)(sr) * TT + kt * 64 + sg * 8 + r * 32 * TT;
            pV[r][0] = *(const uint4*)&vthp[vo];
            pV[r][1] = *(const uint4*)&vtlp[vo];
        }
        __syncthreads();   // prev tile's PV frag reads complete
        #pragma unroll
        for (int r = 0; r < 2; ++r) {
            int idx = tid + r * 256;
            int row = idx >> 3, gg = idx & 7;
            *(uint4*)&Kh[row][gg * 8] = pK[r][0];
            *(uint4*)&Kl[row][gg * 8] = pK[r][1];
            *(uint4*)&Vth[sr + r * 32][sg * 8] = pV[r][0];
            *(uint4*)&Vtl[sr + r * 32][sg * 8] = pV[r][1];
        }
        __syncthreads();

        // S - 24 = Q.K^T - 24 (3-term split; C-init carries the -24)
        f4 accs[2][4];
        #pragma unroll
        for (int rt = 0; rt < 2; ++rt)
            #pragma unroll
            for (int ct = 0; ct < 4; ++ct)
                accs[rt][ct] = f4{-24.f, -24.f, -24.f, -24.f};
        #pragma unroll
        for (int kk = 0; kk < 2; ++kk)
            #pragma unroll
            for (int ct = 0; ct < 4; ++ct) {
                s8b bh = *(const s8b*)&Kh[ct * 16 + lcol][kk * 32 + quad * 8];
                s8b bl = *(const s8b*)&Kl[ct * 16 + lcol][kk * 32 + quad * 8];
                #pragma unroll
                for (int rt = 0; rt < 2; ++rt) {
                    accs[rt][ct] = __builtin_amdgcn_mfma_f32_16x16x32_bf16(qh[rt][kk], bh, accs[rt][ct], 0, 0, 0);
                    accs[rt][ct] = __builtin_amdgcn_mfma_f32_16x16x32_bf16(qh[rt][kk], bl, accs[rt][ct], 0, 0, 0);
                    accs[rt][ct] = __builtin_amdgcn_mfma_f32_16x16x32_bf16(ql[rt][kk], bh, accs[rt][ct], 0, 0, 0);
                }
            }
        __syncthreads();   // all K frag reads done; Kh/Kl reusable as P

        // p = exp2(s-24); per-lane partial row-sum; P -> LDS, b64 permuted:
        // col c=ct*16+lcol stored at slot (c&15)*4+(c>>4) = lcol*4+ct
        #pragma unroll
        for (int rt = 0; rt < 2; ++rt)
            #pragma unroll
            for (int reg = 0; reg < 4; ++reg) {
                int pr = pbase + rt * 16 + quad * 4 + reg;
                float p0 = fexp2(accs[rt][0][reg]);
                float p1 = fexp2(accs[rt][1][reg]);
                float p2 = fexp2(accs[rt][2][reg]);
                float p3 = fexp2(accs[rt][3][reg]);
                lsum[rt][reg] += (p0 + p1) + (p2 + p3);
                *(short4*)&Pb[pr][lcol * 4] =
                    make_short4((short)bfh(p0), (short)bfh(p1),
                                (short)bfh(p2), (short)bfh(p3));
            }

        // O += P.V (2-term; A rows wave-private -> no barrier). Both P and
        // Vt use the same permuted k order -> contraction exact.
        #pragma unroll
        for (int kk = 0; kk < 2; ++kk) {
            s8b pa[2];
            #pragma unroll
            for (int rt = 0; rt < 2; ++rt)
                pa[rt] = *(const s8b*)&Pb[pbase + rt * 16 + lcol][kk * 32 + quad * 8];
            #pragma unroll
            for (int dt = 0; dt < 4; ++dt) {
                s8b vh = *(const s8b*)&Vth[dt * 16 + lcol][kk * 32 + quad * 8];
                s8b vl = *(const s8b*)&Vtl[dt * 16 + lcol][kk * 32 + quad * 8];
                #pragma unroll
                for (int rt = 0; rt < 2; ++rt) {
                    acco[rt][dt] = __builtin_amdgcn_mfma_f32_16x16x32_bf16(pa[rt], vh, acco[rt][dt], 0, 0, 0);
                    acco[rt][dt] = __builtin_amdgcn_mfma_f32_16x16x32_bf16(pa[rt], vl, acco[rt][dt], 0, 0, 0);
                }
            }
        }
    }

    // Final: reduce l across the 16 lanes of each quad, normalize, store
    #pragma unroll
    for (int rt = 0; rt < 2; ++rt)
        #pragma unroll
        for (int reg = 0; reg < 4; ++reg) {
            float rs = lsum[rt][reg];
            #pragma unroll
            for (int off = 1; off <= 8; off <<= 1)
                rs += __shfl_xor(rs, off);
            float inv = 1.f / rs;
            int t = qt * 128 + w * 32 + rt * 16 + quad * 4 + reg;
            float* dst = &out[((size_t)(nn * TT + t)) * EE + hh * DD];
            #pragma unroll
            for (int dt = 0; dt < 4; ++dt)
                dst[dt * 16 + lcol] = acco[rt][dt][reg] * inv;
        }
}

// ---------------------------------------------------------------------------
extern "C" void kernel_launch(void* const* d_in, const int* in_sizes, int n_in,
                              void* d_out, int out_size, void* d_ws, size_t ws_size,
                              hipStream_t stream) {
    const float* x  = (const float*)d_in[0];
    const float* Wq = (const float*)d_in[1];
    const float* Wk = (const float*)d_in[2];
    const float* Wv = (const float*)d_in[3];
    float* out = (float*)d_out;
    unsigned short* ws = (unsigned short*)d_ws;
    // ws layout (ushorts): Qh,Ql,Kh,Kl,Vth,Vtl (6*PLANE_S), Wh,Wl (2*3*WMAT),
    // xh,xl (2*XSZ). Total ~107.7 MB.
    unsigned short* whp = ws + 6 * PLANE_S;
    unsigned short* wlp = whp + 3 * (size_t)WMAT;
    unsigned short* xhp = wlp + 3 * (size_t)WMAT;
    unsigned short* xlp = xhp + XSZ;

    dim3 block(256);
    prep_x<<<dim3(6144), block, 0, stream>>>(x, xhp, xlp);
    prep_w<<<dim3(576, 3), block, 0, stream>>>(Wq, Wk, Wv, whp, wlp);
    qkv_mfma<<<dim3(64, 12), block, 0, stream>>>(xhp, xlp, whp, wlp, ws);
    attn_mfma<<<dim3(768), block, 0, stream>>>(ws, out);
}

// Round 5
// 296.964 us; speedup vs baseline: 1.9781x; 1.9781x over previous
//
#include <hip/hip_runtime.h>
#include <math.h>

#define NB 4
#define TT 2048
#define EE 768
#define HH 12
#define DD 64
#define NH (NB*HH)                          // 48
#define PLANE_S ((size_t)NH * TT * DD)      // 6291456 ushorts per bf16 plane
#define WMAT (EE*EE)                        // 589824
#define XSZ ((size_t)NB * TT * EE)          // 6291456
#define QSCALE 0.18033688011112042f         // 0.125 * log2(e): base-2 softmax

typedef __attribute__((ext_vector_type(8))) short s8b;   // 8 bf16 (4 VGPR)
typedef __attribute__((ext_vector_type(4))) float f4;    // MFMA C/D

// fp32 -> bf16 RNE and hi/lo split: x ~= hi + lo, err ~ 2^-18 |x|
__device__ inline unsigned short bfh(float x) {
    unsigned u = __float_as_uint(x);
    return (unsigned short)((u + 0x7fffu + ((u >> 16) & 1u)) >> 16);
}
__device__ inline float bff(unsigned short s) { return __uint_as_float(((unsigned)s) << 16); }
__device__ inline void split1(float x, unsigned short& h, unsigned short& l) {
    h = bfh(x); l = bfh(x - bff(h));
}
__device__ inline float fexp2(float x) {
#if __has_builtin(__builtin_amdgcn_exp2f)
    return __builtin_amdgcn_exp2f(x);
#else
    return __expf(x * 0.6931471805599453f);
#endif
}

// async global->LDS DMA, 16 B per lane. LDS dest = base + lane*16 (HW rule);
// per-lane global gather address carries the XOR bank-swizzle.
__device__ __forceinline__ void async16(const void* g, void* l) {
    __builtin_amdgcn_global_load_lds(
        (const __attribute__((address_space(1))) unsigned int*)g,
        (__attribute__((address_space(3))) unsigned int*)l, 16, 0, 0);
}

// ---------------------------------------------------------------------------
// Kernel 0a/0b: pre-split x and W to bf16 hi/lo planes (once).
// ---------------------------------------------------------------------------
__global__ __launch_bounds__(256) void prep_x(
    const float* __restrict__ x, unsigned short* __restrict__ xh,
    unsigned short* __restrict__ xl)
{
    const int base = blockIdx.x * 1024 + threadIdx.x * 4;
    float4 v = *(const float4*)&x[base];
    unsigned short h0,l0,h1,l1,h2,l2,h3,l3;
    split1(v.x,h0,l0); split1(v.y,h1,l1); split1(v.z,h2,l2); split1(v.w,h3,l3);
    *(short4*)&xh[base] = make_short4((short)h0,(short)h1,(short)h2,(short)h3);
    *(short4*)&xl[base] = make_short4((short)l0,(short)l1,(short)l2,(short)l3);
}

__global__ __launch_bounds__(256) void prep_w(
    const float* __restrict__ Wq, const float* __restrict__ Wk,
    const float* __restrict__ Wv, unsigned short* __restrict__ wh,
    unsigned short* __restrict__ wl)
{
    const int mat = blockIdx.y;
    const float* __restrict__ W = (mat == 0) ? Wq : (mat == 1) ? Wk : Wv;
    const int base = blockIdx.x * 1024 + threadIdx.x * 4;
    float4 v = *(const float4*)&W[base];
    unsigned short h0,l0,h1,l1,h2,l2,h3,l3;
    split1(v.x,h0,l0); split1(v.y,h1,l1); split1(v.z,h2,l2); split1(v.w,h3,l3);
    size_t o = (size_t)mat * WMAT + base;
    *(short4*)&wh[o] = make_short4((short)h0,(short)h1,(short)h2,(short)h3);
    *(short4*)&wl[o] = make_short4((short)l0,(short)l1,(short)l2,(short)l3);
}

// ---------------------------------------------------------------------------
// Kernel 1: fused QKV projection (bf16x3 MFMA), pure-copy staging, loads
// stored to LDS immediately (NO cross-barrier register liveness -> no spill).
// Outputs: Qh/Ql (pre-scaled), Kh/Kl [nh][t][d]; Vth/Vtl transposed
// [nh][d][t'] with t' permuted per 64-group by s(u)=(u&15)*4+(u>>4)
// (matches attn's P order; exact).
// ---------------------------------------------------------------------------
__global__ __launch_bounds__(256, 3) void qkv_mfma(
    const unsigned short* __restrict__ xh,
    const unsigned short* __restrict__ xl,
    const unsigned short* __restrict__ whp,
    const unsigned short* __restrict__ wlp,
    unsigned short* __restrict__ ws)
{
    const int mt  = blockIdx.x;     // 0..63
    const int h   = blockIdx.y;     // 0..11
    const int tid = threadIdx.x;
    const int w    = tid >> 6;
    const int ln   = tid & 63;
    const int quad = ln >> 4;
    const int lcol = ln & 15;

    union Smem {
        struct { unsigned short Ah[128][40], Al[128][40],
                                Bh[3][64][40], Bl[3][64][40]; } s;   // 51200 B
        struct { unsigned short Vh[64][136], Vl[64][136]; } t;        // 34816 B
    };
    __shared__ __align__(16) union Smem u;

    f4 acc[3][2][4];
    #pragma unroll
    for (int s = 0; s < 3; ++s)
        #pragma unroll
        for (int rt = 0; rt < 2; ++rt)
            #pragma unroll
            for (int ct = 0; ct < 4; ++ct)
                acc[s][rt][ct] = f4{0.f, 0.f, 0.f, 0.f};

    const int m0 = mt * 128;
    const int brow = tid >> 2, bgg = tid & 3;

    for (int kt = 0; kt < EE; kt += 32) {
        __syncthreads();
        // A: 128x32 hi/lo, 512 granules/plane, 2/thread, load->store direct
        #pragma unroll
        for (int r = 0; r < 2; ++r) {
            int idx = tid + r * 256;
            int row = idx >> 2, gg = idx & 3;
            size_t go = (size_t)(m0 + row) * EE + kt + gg * 8;
            *(uint4*)&u.s.Ah[row][gg * 8] = *(const uint4*)&xh[go];
            *(uint4*)&u.s.Al[row][gg * 8] = *(const uint4*)&xl[go];
        }
        // B: 3 x 64x32 hi/lo, 1 granule/thread/mat/plane
        #pragma unroll
        for (int r = 0; r < 3; ++r) {
            size_t go = (size_t)r * WMAT + (size_t)(h * 64 + brow) * EE + kt + bgg * 8;
            *(uint4*)&u.s.Bh[r][brow][bgg * 8] = *(const uint4*)&whp[go];
            *(uint4*)&u.s.Bl[r][brow][bgg * 8] = *(const uint4*)&wlp[go];
        }
        __syncthreads();

        s8b ah[2], al[2];
        #pragma unroll
        for (int rt = 0; rt < 2; ++rt) {
            ah[rt] = *(const s8b*)&u.s.Ah[w * 32 + rt * 16 + lcol][quad * 8];
            al[rt] = *(const s8b*)&u.s.Al[w * 32 + rt * 16 + lcol][quad * 8];
        }
        #pragma unroll
        for (int s = 0; s < 3; ++s)
            #pragma unroll
            for (int ct = 0; ct < 4; ++ct) {
                s8b bh = *(const s8b*)&u.s.Bh[s][ct * 16 + lcol][quad * 8];
                s8b bl = *(const s8b*)&u.s.Bl[s][ct * 16 + lcol][quad * 8];
                #pragma unroll
                for (int rt = 0; rt < 2; ++rt) {
                    acc[s][rt][ct] = __builtin_amdgcn_mfma_f32_16x16x32_bf16(ah[rt], bh, acc[s][rt][ct], 0, 0, 0);
                    acc[s][rt][ct] = __builtin_amdgcn_mfma_f32_16x16x32_bf16(ah[rt], bl, acc[s][rt][ct], 0, 0, 0);
                    acc[s][rt][ct] = __builtin_amdgcn_mfma_f32_16x16x32_bf16(al[rt], bh, acc[s][rt][ct], 0, 0, 0);
                }
            }
    }

    unsigned short* qhp = ws;
    unsigned short* qlp = ws + PLANE_S;
    unsigned short* khp = ws + 2 * PLANE_S;
    unsigned short* klp = ws + 3 * PLANE_S;
    unsigned short* vthp = ws + 4 * PLANE_S;
    unsigned short* vtlp = ws + 5 * PLANE_S;

    const int n = m0 >> 11;
    const int tb = m0 & 2047;
    const int nh = n * HH + h;

    // Q (scaled) and K: direct hi/lo stores, [nh][t][d]
    #pragma unroll
    for (int rt = 0; rt < 2; ++rt)
        #pragma unroll
        for (int reg = 0; reg < 4; ++reg) {
            int t = tb + w * 32 + rt * 16 + quad * 4 + reg;
            size_t ro = ((size_t)nh * TT + t) * DD;
            #pragma unroll
            for (int ct = 0; ct < 4; ++ct) {
                unsigned short hi, lo;
                split1(acc[0][rt][ct][reg] * QSCALE, hi, lo);
                qhp[ro + ct * 16 + lcol] = hi;
                qlp[ro + ct * 16 + lcol] = lo;
                split1(acc[1][rt][ct][reg], hi, lo);
                khp[ro + ct * 16 + lcol] = hi;
                klp[ro + ct * 16 + lcol] = lo;
            }
        }

    // V: transpose+permute through LDS -> [nh][d][t']
    // slot(u) = (u&15)*4 + (u>>4) within each 64-key group
    __syncthreads();
    #pragma unroll
    for (int rt = 0; rt < 2; ++rt)
        #pragma unroll
        for (int reg = 0; reg < 4; ++reg) {
            int slot = (w >> 1) * 64 + (quad * 4 + reg) * 4 + (w & 1) * 2 + rt;
            #pragma unroll
            for (int ct = 0; ct < 4; ++ct) {
                unsigned short hi, lo;
                split1(acc[2][rt][ct][reg], hi, lo);
                u.t.Vh[ct * 16 + lcol][slot] = hi;
                u.t.Vl[ct * 16 + lcol][slot] = lo;
            }
        }
    __syncthreads();
    #pragma unroll
    for (int r = 0; r < 8; ++r) {
        int idx = tid + r * 256;
        int pl = idx >> 10, rem = idx & 1023;
        int d = rem >> 4, gg = rem & 15;
        uint4 v = (pl == 0) ? *(const uint4*)&u.t.Vh[d][gg * 8]
                            : *(const uint4*)&u.t.Vl[d][gg * 8];
        unsigned short* dst = (pl == 0) ? vthp : vtlp;
        *(uint4*)&dst[(size_t)nh * (DD * TT) + (size_t)d * TT + tb + gg * 8] = v;
    }
}

// ---------------------------------------------------------------------------
// Kernel 2: MFMA flash attention. Unpadded 64x64 LDS tiles with XOR bank
// swizzle (granule g stored at g ^ (row&7)); staged via global_load_lds
// (swizzle folded into the per-lane gather address, lane-constant).
// Fixed-max base-2 softmax; P (b64, permuted k-order) reuses Kh/Kl.
// LDS = 32 KB; grid 768 = 3 blocks/CU exact.
// ---------------------------------------------------------------------------
__global__ __launch_bounds__(256, 3) void attn_mfma(
    const unsigned short* __restrict__ ws, float* __restrict__ out)
{
    const int bid = blockIdx.x;          // 0..767
    const int xcd = bid & 7;
    const int r0  = bid >> 3;
    const int qt  = r0 & 15;
    const int nh  = xcd * 6 + (r0 >> 4);
    const int nn  = nh / HH, hh = nh % HH;

    const int tid = threadIdx.x;
    const int w    = tid >> 6;
    const int ln   = tid & 63;
    const int quad = ln >> 4;
    const int lcol = ln & 15;

    const unsigned short* qhp = ws                + (size_t)nh * (TT * DD);
    const unsigned short* qlp = ws +     PLANE_S  + (size_t)nh * (TT * DD);
    const unsigned short* khp = ws + 2 * PLANE_S  + (size_t)nh * (TT * DD);
    const unsigned short* klp = ws + 3 * PLANE_S  + (size_t)nh * (TT * DD);
    const unsigned short* vthp = ws + 4 * PLANE_S + (size_t)nh * (DD * TT);
    const unsigned short* vtlp = ws + 5 * PLANE_S + (size_t)nh * (DD * TT);

    __shared__ __align__(16) unsigned short Kh[64*64], Kl[64*64];
    __shared__ __align__(16) unsigned short Vth[64*64], Vtl[64*64];

    // Lane-constant gather offsets (bytes). LDS slot (row, j) receives
    // logical granule g = j ^ (row&7); row = chunk*8 + (ln>>3), j = ln&7.
    const int rchk = ln >> 3;
    const int gsrc = (ln & 7) ^ rchk;
    const int koff = rchk * 128 + gsrc * 16;    // K planes: 128 B rows
    const int voff = rchk * 4096 + gsrc * 16;   // V planes: row stride 4096 B

    // Q fragments (unswizzled global, once)
    s8b qh[2][2], ql[2][2];
    #pragma unroll
    for (int rt = 0; rt < 2; ++rt)
        #pragma unroll
        for (int kk = 0; kk < 2; ++kk) {
            int qrow = qt * 128 + w * 32 + rt * 16 + lcol;
            size_t o = (size_t)qrow * DD + kk * 32 + quad * 8;
            qh[rt][kk] = *(const s8b*)&qhp[o];
            ql[rt][kk] = *(const s8b*)&qlp[o];
        }

    f4 acco[2][4];
    float lsum[2][4];
    #pragma unroll
    for (int rt = 0; rt < 2; ++rt)
        #pragma unroll
        for (int j = 0; j < 4; ++j) { acco[rt][j] = f4{0.f,0.f,0.f,0.f}; lsum[rt][j] = 0.f; }

    unsigned short* __restrict__ Pb = (w < 2) ? Kh : Kl;
    const int pbase = (w & 1) * 32;

    for (int kt = 0; kt < TT / 64; ++kt) {
        __syncthreads();   // (A) prev tile's frag reads complete
        // Async DMA: 32 chunks of 1 KB (4 planes x 8); wave w takes 2/plane
        #pragma unroll
        for (int r = 0; r < 2; ++r) {
            int c = 2 * w + r;
            async16((const char*)khp  + (size_t)kt * 8192  + c * 1024  + koff, &Kh[c * 512]);
            async16((const char*)klp  + (size_t)kt * 8192  + c * 1024  + koff, &Kl[c * 512]);
            async16((const char*)vthp + (size_t)c * 32768  + kt * 128  + voff, &Vth[c * 512]);
            async16((const char*)vtlp + (size_t)c * 32768  + kt * 128  + voff, &Vtl[c * 512]);
        }
        __syncthreads();   // (B) vmcnt(0) drain -> tiles visible

        // S - 24 = Q.K^T - 24 (3-term split)
        f4 accs[2][4];
        #pragma unroll
        for (int rt = 0; rt < 2; ++rt)
            #pragma unroll
            for (int ct = 0; ct < 4; ++ct)
                accs[rt][ct] = f4{-24.f, -24.f, -24.f, -24.f};
        #pragma unroll
        for (int kk = 0; kk < 2; ++kk)
            #pragma unroll
            for (int ct = 0; ct < 4; ++ct) {
                int off = (ct * 16 + lcol) * 64 + ((kk * 4 + quad) ^ (lcol & 7)) * 8;
                s8b bh = *(const s8b*)&Kh[off];
                s8b bl = *(const s8b*)&Kl[off];
                #pragma unroll
                for (int rt = 0; rt < 2; ++rt) {
                    accs[rt][ct] = __builtin_amdgcn_mfma_f32_16x16x32_bf16(qh[rt][kk], bh, accs[rt][ct], 0, 0, 0);
                    accs[rt][ct] = __builtin_amdgcn_mfma_f32_16x16x32_bf16(qh[rt][kk], bl, accs[rt][ct], 0, 0, 0);
                    accs[rt][ct] = __builtin_amdgcn_mfma_f32_16x16x32_bf16(ql[rt][kk], bh, accs[rt][ct], 0, 0, 0);
                }
            }
        __syncthreads();   // (C) all K frag reads done; Kh/Kl reusable as P

        // p = exp2(s-24); P -> LDS b64, permuted slot = lcol*4+ct, swizzled
        #pragma unroll
        for (int rt = 0; rt < 2; ++rt)
            #pragma unroll
            for (int reg = 0; reg < 4; ++reg) {
                int pr = pbase + rt * 16 + quad * 4 + reg;
                float p0 = fexp2(accs[rt][0][reg]);
                float p1 = fexp2(accs[rt][1][reg]);
                float p2 = fexp2(accs[rt][2][reg]);
                float p3 = fexp2(accs[rt][3][reg]);
                lsum[rt][reg] += (p0 + p1) + (p2 + p3);
                int po = pr * 64 + (((lcol >> 1) ^ (pr & 7)) * 8) + (lcol & 1) * 4;
                *(short4*)&Pb[po] =
                    make_short4((short)bfh(p0), (short)bfh(p1),
                                (short)bfh(p2), (short)bfh(p3));
            }

        // O += P.V (2-term; P rows wave-private -> no barrier)
        #pragma unroll
        for (int kk = 0; kk < 2; ++kk) {
            s8b pa[2];
            #pragma unroll
            for (int rt = 0; rt < 2; ++rt) {
                int po = (pbase + rt * 16 + lcol) * 64 + ((kk * 4 + quad) ^ (lcol & 7)) * 8;
                pa[rt] = *(const s8b*)&Pb[po];
            }
            #pragma unroll
            for (int dt = 0; dt < 4; ++dt) {
                int vo = (dt * 16 + lcol) * 64 + ((kk * 4 + quad) ^ (lcol & 7)) * 8;
                s8b vh = *(const s8b*)&Vth[vo];
                s8b vl = *(const s8b*)&Vtl[vo];
                #pragma unroll
                for (int rt = 0; rt < 2; ++rt) {
                    acco[rt][dt] = __builtin_amdgcn_mfma_f32_16x16x32_bf16(pa[rt], vh, acco[rt][dt], 0, 0, 0);
                    acco[rt][dt] = __builtin_amdgcn_mfma_f32_16x16x32_bf16(pa[rt], vl, acco[rt][dt], 0, 0, 0);
                }
            }
        }
    }

    // Final: reduce l across the 16 lanes of each quad, normalize, store
    #pragma unroll
    for (int rt = 0; rt < 2; ++rt)
        #pragma unroll
        for (int reg = 0; reg < 4; ++reg) {
            float rs = lsum[rt][reg];
            #pragma unroll
            for (int off = 1; off <= 8; off <<= 1)
                rs += __shfl_xor(rs, off);
            float inv = 1.f / rs;
            int t = qt * 128 + w * 32 + rt * 16 + quad * 4 + reg;
            float* dst = &out[((size_t)(nn * TT + t)) * EE + hh * DD];
            #pragma unroll
            for (int dt = 0; dt < 4; ++dt)
                dst[dt * 16 + lcol] = acco[rt][dt][reg] * inv;
        }
}

// ---------------------------------------------------------------------------
extern "C" void kernel_launch(void* const* d_in, const int* in_sizes, int n_in,
                              void* d_out, int out_size, void* d_ws, size_t ws_size,
                              hipStream_t stream) {
    const float* x  = (const float*)d_in[0];
    const float* Wq = (const float*)d_in[1];
    const float* Wk = (const float*)d_in[2];
    const float* Wv = (const float*)d_in[3];
    float* out = (float*)d_out;
    unsigned short* ws = (unsigned short*)d_ws;
    // ws (ushorts): Qh,Ql,Kh,Kl,Vth,Vtl (6*PLANE_S), Wh,Wl (6*WMAT),
    // xh,xl (2*XSZ). ~102.8 MB.
    unsigned short* whp = ws + 6 * PLANE_S;
    unsigned short* wlp = whp + 3 * (size_t)WMAT;
    unsigned short* xhp = wlp + 3 * (size_t)WMAT;
    unsigned short* xlp = xhp + XSZ;

    dim3 block(256);
    prep_x<<<dim3(6144), block, 0, stream>>>(x, xhp, xlp);
    prep_w<<<dim3(576, 3), block, 0, stream>>>(Wq, Wk, Wv, whp, wlp);
    qkv_mfma<<<dim3(64, 12), block, 0, stream>>>(xhp, xlp, whp, wlp, ws);
    attn_mfma<<<dim3(768), block, 0, stream>>>(ws, out);
}